// Round 13
// baseline (375.746 us; speedup 1.0000x reference)
//
#include <hip/hip_runtime.h>

typedef unsigned short u16;
typedef unsigned char  u8;
typedef unsigned int   u32;
typedef unsigned long long u64;
typedef __attribute__((ext_vector_type(8))) short short8;
typedef __attribute__((ext_vector_type(4))) float f32x4;
typedef __attribute__((ext_vector_type(2))) float f32x2;

// keep loaded fragments materialized (asm output can't be rematerialized)
#define PIN8(v) asm volatile("" : "+v"(v))

__device__ __forceinline__ float b2f(u16 u) { return __uint_as_float(((u32)u) << 16); }
__device__ __forceinline__ u16 f2b(float f) {
    u32 i = __float_as_uint(f);
    return (u16)((i + 0x7FFFu + ((i >> 16) & 1u)) >> 16);   // RNE
}
__device__ __forceinline__ float gelu_f(float v) {
    return 0.5f * v * (1.f + erff(v * 0.70710678118654752f));  // exact-erf GELU
}
__device__ __forceinline__ float ldf(const void* p, int i, int f32) {
    return f32 ? ((const float*)p)[i] : b2f(((const u16*)p)[i]);
}

// ---- OCP e4m3fn decode/encode (manual fallback) ----
__device__ __forceinline__ float fp8_dec(u32 v) {  // low 8 bits used
    u32 bits = ((v & 0x80u) << 24) | ((v & 0x7Fu) << 20);
    return __uint_as_float(bits) * 1.3292279957849159e36f;  // *2^120
}
__device__ __forceinline__ u32 fp8_enc(float x) {
    u32 b = __float_as_uint(x);
    u32 s = (b >> 24) & 0x80u;
    float ax = fminf(__uint_as_float(b & 0x7FFFFFFFu), 448.f);
    u32 r;
    if (ax < 0.015625f) {
        r = (u32)(ax * 512.f + 0.5f);
    } else {
        u32 ab = __float_as_uint(ax);
        u32 rb = ab + 0x7FFFFu + ((ab >> 20) & 1u);   // RNE to 3-bit mantissa
        int e8 = (int)(rb >> 23) - 120;
        u32 m = (rb >> 20) & 7u;
        if (e8 > 15) { e8 = 15; m = 6u; }
        r = ((u32)e8 << 3) | m;
    }
    return s | r;
}

// HW fp8 converters (gfx950: OCP e4m3fn) with manual fallback
__device__ __forceinline__ f32x2 dec2_fp8(u32 v) {  // low 16 bits = 2 fp8
#if __has_builtin(__builtin_amdgcn_cvt_pk_f32_fp8)
    return __builtin_amdgcn_cvt_pk_f32_fp8((int)v, false);
#else
    f32x2 r; r[0] = fp8_dec(v); r[1] = fp8_dec(v >> 8); return r;
#endif
}
__device__ __forceinline__ u32 pk4_fp8(float v0, float v1, float v2, float v3) {
#if __has_builtin(__builtin_amdgcn_cvt_pk_fp8_f32)
    int p = __builtin_amdgcn_cvt_pk_fp8_f32(v0, v1, 0, false);
    p = __builtin_amdgcn_cvt_pk_fp8_f32(v2, v3, p, true);
    return (u32)p;
#else
    return fp8_enc(v0) | (fp8_enc(v1) << 8) | (fp8_enc(v2) << 16) | (fp8_enc(v3) << 24);
#endif
}

// ---------------- dtype probe ----------------
__global__ void probe_kernel(const int* __restrict__ ei, const u16* __restrict__ xw,
                             int* __restrict__ mode) {
    int lane = threadIdx.x;  // 64
    int v = (lane < 8) ? ei[2 * lane + 1] : 0;
    unsigned long long nz = __ballot(v != 0);
    u16 h = xw[2 * lane];
    int e = (h >> 7) & 0xFF;
    unsigned long long pl = __ballot(e >= 100 && e <= 140);
    if (lane == 0) {
        mode[0] = (nz == 0ULL) ? 1 : 0;
        mode[1] = (__popcll(pl) >= 48) ? 0 : 1;
    }
}

// ---------------- fallback ----------------
__global__ __launch_bounds__(256) void fallback_kernel(const void* __restrict__ rr,
                                                       const void* __restrict__ al,
                                                       const int* __restrict__ mode,
                                                       void* __restrict__ out, int N) {
    int i = blockIdx.x * 256 + threadIdx.x;
    if (i >= N) return;
    int f32 = mode ? mode[1] : 0;
    float a = 1.f / (1.f + expf(-ldf(al, 0, f32)));
    float v = a * ldf(rr, i, f32);
    if (f32) ((float*)out)[i] = v; else ((u16*)out)[i] = f2b(v);
}

// ---------------- CSR build (legacy global-atomic path, ws fallback) ----------------
__global__ __launch_bounds__(256) void hist_kernel(const int* __restrict__ ei, int E, int N,
                                                   const int* __restrict__ mode,
                                                   int* __restrict__ deg) {
    int i = blockIdx.x * 256 + threadIdx.x;
    if (i >= E) return;
    int m64 = mode[0];
    int d = m64 ? ei[2 * E + 2 * i] : ei[E + i];
    if ((unsigned)d < (unsigned)N) atomicAdd(&deg[d], 1);
}

// per-chunk bucket histogram, CHUNK=2048, 256 threads. NO GLOBAL ATOMICS. chist [bucket][chunk].
__global__ __launch_bounds__(256) void bucketHist2_kernel(const int* __restrict__ ei, int E, int N,
                                                          const int* __restrict__ mode, int shift,
                                                          int* __restrict__ chist, int chunks) {
    __shared__ int h[1024];
    int t = threadIdx.x;
#pragma unroll
    for (int j = 0; j < 4; j++) h[t + j * 256] = 0;
    __syncthreads();
    const int m64 = mode[0];
    const int base = blockIdx.x * 2048;
#pragma unroll
    for (int j = 0; j < 8; j++) {
        int i = base + j * 256 + t;
        if (i < E) {
            int d = m64 ? ei[2 * E + 2 * i] : ei[E + i];
            if ((unsigned)d < (unsigned)N) atomicAdd(&h[d >> shift], 1);
        }
    }
    __syncthreads();
#pragma unroll
    for (int j = 0; j < 4; j++) {
        int b = t + j * 256;
        chist[(size_t)b * chunks + blockIdx.x] = h[b];
    }
}

__global__ __launch_bounds__(256) void scanA_kernel(const int* __restrict__ deg,
                                                    int* __restrict__ part) {
    int t = threadIdx.x, lane = t & 63, wv = t >> 6;
    size_t base = (size_t)blockIdx.x * 2048 + (size_t)t * 8;
    int s = 0;
#pragma unroll
    for (int j = 0; j < 8; j++) s += deg[base + j];
    for (int m = 1; m < 64; m <<= 1) s += __shfl_xor(s, m, 64);
    __shared__ int ws4[4];
    if (lane == 0) ws4[wv] = s;
    __syncthreads();
    if (t == 0) part[blockIdx.x] = ws4[0] + ws4[1] + ws4[2] + ws4[3];
}

__global__ void scanB_kernel(int* __restrict__ part, int nb) {
    int lane = threadIdx.x;
    int v = (lane < nb) ? part[lane] : 0;
    int orig = v;
    for (int d = 1; d < 64; d <<= 1) {
        int o = __shfl_up(v, d, 64);
        if (lane >= d) v += o;
    }
    if (lane < nb) part[lane] = v - orig;  // exclusive
}

__global__ __launch_bounds__(256) void scanC_kernel(const int* __restrict__ deg,
                                                    const int* __restrict__ part,
                                                    int* __restrict__ off) {
    int t = threadIdx.x, lane = t & 63, wv = t >> 6;
    size_t base = (size_t)blockIdx.x * 2048 + (size_t)t * 8;
    int v[8];
    int s = 0;
#pragma unroll
    for (int j = 0; j < 8; j++) { v[j] = deg[base + j]; s += v[j]; }
    int incl = s;
    for (int d = 1; d < 64; d <<= 1) {
        int o = __shfl_up(incl, d, 64);
        if (lane >= d) incl += o;
    }
    __shared__ int wsum[4];
    if (lane == 63) wsum[wv] = incl;
    __syncthreads();
    int pre = part[blockIdx.x] + (incl - s);
    for (int w = 0; w < wv; w++) pre += wsum[w];
#pragma unroll
    for (int j = 0; j < 8; j++) { off[base + j] = pre; pre += v[j]; }
    if (blockIdx.x == gridDim.x - 1 && t == 255) off[base + 8] = pre;  // off[NP]
}

// exclusive scan of 1024 bucket counts (one block)
__global__ __launch_bounds__(256) void scanK_kernel(const int* __restrict__ bcnt,
                                                    int* __restrict__ boff) {
    int t = threadIdx.x, lane = t & 63, wv = t >> 6;
    int v[4];
    int s = 0;
#pragma unroll
    for (int j = 0; j < 4; j++) { v[j] = bcnt[t * 4 + j]; s += v[j]; }
    int incl = s;
    for (int d = 1; d < 64; d <<= 1) {
        int o = __shfl_up(incl, d, 64);
        if (lane >= d) incl += o;
    }
    __shared__ int wsum[4];
    if (lane == 63) wsum[wv] = incl;
    __syncthreads();
    int pre = incl - s;
    for (int w = 0; w < wv; w++) pre += wsum[w];
#pragma unroll
    for (int j = 0; j < 4; j++) { boff[t * 4 + j] = pre; pre += v[j]; }
    if (t == 255) boff[1024] = pre;
}

// one WAVE per bucket: chist[b][c] -> exclusive prefix WITHIN row; writes bcnt[b].
__global__ __launch_bounds__(256) void chunkScanPre_kernel(int* __restrict__ chist,
                                                           int* __restrict__ bcnt, int chunks) {
    const int b = (blockIdx.x * 256 + threadIdx.x) >> 6;
    if (b >= 1024) return;
    const int lane = threadIdx.x & 63;
    const int per = (chunks + 63) >> 6;   // <= 32 (bucketPath gated at chunks<=2048)
    int* row = chist + (size_t)b * chunks;
    int v[32];
    int sum = 0;
#pragma unroll
    for (int j = 0; j < 32; j++) {
        int c = lane * per + j;
        v[j] = (j < per && c < chunks) ? row[c] : 0;
        sum += v[j];
    }
    int pre = sum;
    for (int d = 1; d < 64; d <<= 1) {
        int o = __shfl_up(pre, d, 64);
        if (lane >= d) pre += o;
    }
    if (lane == 63) bcnt[b] = pre;        // row total (inclusive of all lanes)
    pre -= sum;                            // exclusive within row
#pragma unroll
    for (int j = 0; j < 32; j++) {
        int c = lane * per + j;
        if (j < per && c < chunks) { row[c] = pre; pre += v[j]; }
    }
}

// single-pass scatter using per-chunk local bases + boff[b] (no global atomics).
__global__ __launch_bounds__(256) void bucketScatter2_kernel(const int* __restrict__ ei, int E, int N,
                                                             const int* __restrict__ mode, int shift,
                                                             const int* __restrict__ cbase,
                                                             const int* __restrict__ boff,
                                                             u64* __restrict__ pairs, int chunks) {
    __shared__ int cur[1024];
    int t = threadIdx.x;
#pragma unroll
    for (int j = 0; j < 4; j++) {
        int b = t + j * 256;
        cur[b] = cbase[(size_t)b * chunks + blockIdx.x] + boff[b];
    }
    __syncthreads();
    const int m64 = mode[0];
    const int base = blockIdx.x * 2048;
#pragma unroll
    for (int j = 0; j < 8; j++) {
        int i = base + j * 256 + t;
        if (i < E) {
            int d = m64 ? ei[2 * E + 2 * i] : ei[E + i];
            if ((unsigned)d >= (unsigned)N) continue;
            int s = m64 ? ei[2 * i] : ei[i];
            if ((unsigned)s >= (unsigned)N) s = 0;
            int p = atomicAdd(&cur[d >> shift], 1);
            pairs[p] = ((u64)(u32)d << 32) | (u32)s;
        }
    }
}

// final fill, two-pass: derive per-node degrees + CSR off[] locally, then place.
__global__ __launch_bounds__(256) void bucketFill2_kernel(const u64* __restrict__ pairs,
                                                          const int* __restrict__ boff,
                                                          int* __restrict__ off,
                                                          int* __restrict__ sorted,
                                                          int shift, int E, int N) {
    __shared__ int cur[2048];
    __shared__ int wsum[4];
    const int b = blockIdx.x;
    const int t = threadIdx.x;
    const int lane = t & 63, wv = t >> 6;
    const int nodes = 1 << shift;          // <= 2048
    const int nbase = b << shift;
    for (int i = t; i < nodes; i += 256) cur[i] = 0;
    __syncthreads();
    const int s0 = boff[b], s1 = boff[b + 1];
    // pass 1: count degrees
    for (int i = s0 + t; i < s1; i += 256) {
        int li = (int)(pairs[i] >> 32) - nbase;
        if ((unsigned)li < (unsigned)nodes) atomicAdd(&cur[li], 1);
    }
    __syncthreads();
    // exclusive scan of cur[0..nodes) + s0; per = nodes/256 rounded up (1..8)
    const int per = (nodes + 255) >> 8;
    int v[8];
    int sum = 0;
#pragma unroll
    for (int j = 0; j < 8; j++) {
        int idx = t * per + j;
        v[j] = (j < per && idx < nodes) ? cur[idx] : 0;
        sum += v[j];
    }
    int incl = sum;
    for (int d = 1; d < 64; d <<= 1) {
        int o = __shfl_up(incl, d, 64);
        if (lane >= d) incl += o;
    }
    if (lane == 63) wsum[wv] = incl;
    __syncthreads();
    int pre = s0 + (incl - sum);
    for (int w = 0; w < wv; w++) pre += wsum[w];
#pragma unroll
    for (int j = 0; j < 8; j++) {
        int idx = t * per + j;
        if (j < per && idx < nodes) {
            cur[idx] = pre;                              // absolute cursor start
            if (nbase + idx <= N) off[nbase + idx] = pre; // CSR offsets (guarded <= N)
            pre += v[j];
        }
    }
    if (t == 255 && nbase + nodes <= N) off[nbase + nodes] = s1;  // idempotent boundary
    __syncthreads();
    // pass 2: place
    for (int i = s0 + t; i < s1; i += 256) {
        u64 pr = pairs[i];
        int li = (int)(pr >> 32) - nbase;
        if ((unsigned)li >= (unsigned)nodes) continue;
        int p = atomicAdd(&cur[li], 1);
        if ((unsigned)p < (unsigned)E) sorted[p] = (int)(u32)pr;
    }
}

// legacy fill (ws fallback)
__global__ __launch_bounds__(256) void fill_kernel(const int* __restrict__ ei, int E, int N,
                                                   const int* __restrict__ mode,
                                                   const int* __restrict__ off,
                                                   int* __restrict__ deg,
                                                   int* __restrict__ sorted) {
    int i = blockIdx.x * 256 + threadIdx.x;
    if (i >= E) return;
    int m64 = mode[0];
    int s = m64 ? ei[2 * i] : ei[i];
    int d = m64 ? ei[2 * E + 2 * i] : ei[E + i];
    if ((unsigned)d >= (unsigned)N) return;
    if ((unsigned)s >= (unsigned)N) s = 0;
    int p = atomicSub(&deg[d], 1) - 1;
    if (p < 0) return;
    int pos = off[d] + p;
    if ((unsigned)pos < (unsigned)E) sorted[pos] = s;
}

// ---------------- weight transpose into bf16 T ----------------
__global__ __launch_bounds__(256) void prep_kernel(const void* __restrict__ Wp, const void* __restrict__ Wl0,
                                                   const void* __restrict__ Wr0, const void* __restrict__ Wl1,
                                                   const void* __restrict__ Wr1, const void* __restrict__ Ws1,
                                                   const int* __restrict__ mode, u16* __restrict__ T) {
    int idx = blockIdx.x * 256 + threadIdx.x;
    int f32 = mode[1];
    if (idx < 81920) {
        int m = idx >> 14, e = idx & 16383, n = e & 127, k = e >> 7;
        const void* s;
        switch (m) {
            case 0: s = Wp; break;
            case 1: s = Wl0; break;
            case 2: s = Wr0; break;
            case 3: s = Wl1; break;
            default: s = Wr1; break;
        }
        T[m * 16384 + n * 128 + k] = f2b(ldf(s, e, f32));
    } else if (idx < 90112) {
        int e = idx - 81920, k = e >> 6, n = e & 63;
        T[81920 + n * 128 + k] = f2b(ldf(Ws1, e, f32));
    }
}

// ---------------- fp8 conversion: H[N][128] -> F[N][128] e4m3 ----------------
template <int F32>
__global__ __launch_bounds__(256) void cvt8_kernel(const void* __restrict__ H, u8* __restrict__ F,
                                                   const int* __restrict__ mode, int NE, int checkMode) {
    if (checkMode && mode[1] != F32) return;
    int i = blockIdx.x * 256 + threadIdx.x;  // pair index
    if (i >= NE) return;
    float x0, x1;
    if (!F32) {
        u32 v = ((const u32*)H)[i];
        x0 = b2f((u16)v); x1 = b2f((u16)(v >> 16));
    } else {
        x0 = ((const float*)H)[2 * i]; x1 = ((const float*)H)[2 * i + 1];
    }
#if __has_builtin(__builtin_amdgcn_cvt_pk_fp8_f32)
    ((u16*)F)[i] = (u16)__builtin_amdgcn_cvt_pk_fp8_f32(x0, x1, 0, false);
#else
    ((u16*)F)[i] = (u16)(fp8_enc(x0) | (fp8_enc(x1) << 8));
#endif
}

// ---------------- fp8 gather aggregation (HW cvt decode) ----------------
// Wave-wide srcs prefetch: lane l vector-loads srcs[s0+l] (one coalesced 256B load covers
// 64 edges), edge srcs via __shfl, row-gathers issue 8-deep back-to-back.
__global__ __launch_bounds__(256) void sagg8_kernel(const u8* __restrict__ F, const int* __restrict__ off,
                                                    const int* __restrict__ srcs, u16* __restrict__ meanO,
                                                    int N, int E) {
    const int node = __builtin_amdgcn_readfirstlane(blockIdx.x * 4 + (threadIdx.x >> 6));
    if (node >= N) return;
    const int lane = threadIdx.x & 63;
    int s0 = off[node], s1 = off[node + 1];
    if (s0 < 0) s0 = 0;
    if (s1 > E) s1 = E;
    if (s1 < s0) s1 = s0;
    const int dg = s1 - s0;
    const float inv = 1.f / (float)(dg > 1 ? dg : 1);
    const u8* Fp = F + lane * 2;
    float a0 = 0.f, a1 = 0.f;
    for (int base = s0; base < s1; base += 64) {
        const int rem = s1 - base;
        const int cnt = rem < 64 ? rem : 64;
        int msrc = srcs[base + (lane < cnt ? lane : 0)];   // one coalesced load = 64 edges
        if ((unsigned)msrc >= (unsigned)N) msrc = 0;
        int e = 0;
        for (; e + 7 < cnt; e += 8) {
            int i0 = __shfl(msrc, e + 0, 64);
            int i1 = __shfl(msrc, e + 1, 64);
            int i2 = __shfl(msrc, e + 2, 64);
            int i3 = __shfl(msrc, e + 3, 64);
            int i4 = __shfl(msrc, e + 4, 64);
            int i5 = __shfl(msrc, e + 5, 64);
            int i6 = __shfl(msrc, e + 6, 64);
            int i7 = __shfl(msrc, e + 7, 64);
            u32 v0 = *(const u16*)(Fp + (size_t)i0 * 128);
            u32 v1 = *(const u16*)(Fp + (size_t)i1 * 128);
            u32 v2 = *(const u16*)(Fp + (size_t)i2 * 128);
            u32 v3 = *(const u16*)(Fp + (size_t)i3 * 128);
            u32 v4 = *(const u16*)(Fp + (size_t)i4 * 128);
            u32 v5 = *(const u16*)(Fp + (size_t)i5 * 128);
            u32 v6 = *(const u16*)(Fp + (size_t)i6 * 128);
            u32 v7 = *(const u16*)(Fp + (size_t)i7 * 128);
            f32x2 d0 = dec2_fp8(v0), d1 = dec2_fp8(v1), d2 = dec2_fp8(v2), d3 = dec2_fp8(v3);
            f32x2 d4 = dec2_fp8(v4), d5 = dec2_fp8(v5), d6 = dec2_fp8(v6), d7 = dec2_fp8(v7);
            a0 += (d0[0] + d1[0]) + (d2[0] + d3[0]) + (d4[0] + d5[0]) + (d6[0] + d7[0]);
            a1 += (d0[1] + d1[1]) + (d2[1] + d3[1]) + (d4[1] + d5[1]) + (d6[1] + d7[1]);
        }
        for (; e + 3 < cnt; e += 4) {
            int i0 = __shfl(msrc, e + 0, 64);
            int i1 = __shfl(msrc, e + 1, 64);
            int i2 = __shfl(msrc, e + 2, 64);
            int i3 = __shfl(msrc, e + 3, 64);
            u32 v0 = *(const u16*)(Fp + (size_t)i0 * 128);
            u32 v1 = *(const u16*)(Fp + (size_t)i1 * 128);
            u32 v2 = *(const u16*)(Fp + (size_t)i2 * 128);
            u32 v3 = *(const u16*)(Fp + (size_t)i3 * 128);
            f32x2 d0 = dec2_fp8(v0), d1 = dec2_fp8(v1), d2 = dec2_fp8(v2), d3 = dec2_fp8(v3);
            a0 += (d0[0] + d1[0]) + (d2[0] + d3[0]);
            a1 += (d0[1] + d1[1]) + (d2[1] + d3[1]);
        }
        for (; e < cnt; ++e) {
            int i0 = __shfl(msrc, e, 64);
            f32x2 d0 = dec2_fp8(*(const u16*)(Fp + (size_t)i0 * 128));
            a0 += d0[0];
            a1 += d0[1];
        }
    }
    *(u32*)(meanO + (size_t)node * 128 + lane * 2) = (u32)f2b(a0 * inv) | ((u32)f2b(a1 * inv) << 16);
}

// ---------------- bf16/f32 direct-gather aggregation (ws fallback) ----------------
template <int F32>
__global__ __launch_bounds__(256) void saggb_kernel(const void* __restrict__ H, const int* __restrict__ off,
                                                    const int* __restrict__ srcs, u16* __restrict__ meanO,
                                                    int N, int E, const int* __restrict__ mode, int mcheck) {
    if (mcheck && mode[1] != F32) return;
    const int node = __builtin_amdgcn_readfirstlane(blockIdx.x * 4 + (threadIdx.x >> 6));
    if (node >= N) return;
    const int lane = threadIdx.x & 63;
    int s0 = off[node], s1 = off[node + 1];
    if (s0 < 0) s0 = 0;
    if (s1 > E) s1 = E;
    if (s1 < s0) s1 = s0;
    const int dg = s1 - s0;
    const float inv = 1.f / (float)(dg > 1 ? dg : 1);
    float a0 = 0.f, a1 = 0.f;
    if (!F32) {
        const u32* Hp = (const u32*)H + lane;   // row = 64 u32
        for (int e = s0; e < s1; ++e) {
            int i0 = srcs[e];
            if ((unsigned)i0 >= (unsigned)N) i0 = 0;
            u32 v0 = Hp[(size_t)i0 << 6];
            a0 += __uint_as_float(v0 << 16);
            a1 += __uint_as_float(v0 & 0xFFFF0000u);
        }
    } else {
        const float* Hp = (const float*)H + 2 * lane;   // row = 128 f32
        for (int e = s0; e < s1; ++e) {
            int i0 = srcs[e];
            if ((unsigned)i0 >= (unsigned)N) i0 = 0;
            const float2 w0 = *(const float2*)(Hp + ((size_t)i0 << 7));
            a0 += w0.x;
            a1 += w0.y;
        }
    }
    *(u32*)(meanO + (size_t)node * 128 + lane * 2) = (u32)f2b(a0 * inv) | ((u32)f2b(a1 * inv) << 16);
}

// ---------------- MFMA GEMM pieces ----------------
__device__ __forceinline__ uint4 packbf8(f32x4 a, f32x4 b) {
    uint4 o;
    o.x = (u32)f2b(a[0]) | ((u32)f2b(a[1]) << 16);
    o.y = (u32)f2b(a[2]) | ((u32)f2b(a[3]) << 16);
    o.z = (u32)f2b(b[0]) | ((u32)f2b(b[1]) << 16);
    o.w = (u32)f2b(b[2]) | ((u32)f2b(b[3]) << 16);
    return o;
}

// Stage a 32-row x 128-col bf16 tile into LDS with XOR swizzle ^((row&7)<<4).
// Thread t: row r=t>>3, 32B chunk (t&3... (t&7)*32 of the 256B row. 2 (4) indep loads.
template <int F32>
__device__ __forceinline__ void stageTile32(const void* __restrict__ src, u16* __restrict__ lds,
                                            long tb, int N, int t) {
    const int r = t >> 3;                 // 0..31
    long gr = tb + r;
    if (gr >= N) gr = N - 1;
    const int cb = (t & 7) * 32;          // byte offset within 256B bf16 row
    const int swz = (r & 7) << 4;
    char* lp = (char*)lds + r * 256;
    if (!F32) {
        const char* gp = (const char*)src + gr * 256 + cb;
        uint4 v0 = *(const uint4*)(gp + 0);
        uint4 v1 = *(const uint4*)(gp + 16);
        *(uint4*)(lp + ((cb + 0) ^ swz)) = v0;
        *(uint4*)(lp + ((cb + 16) ^ swz)) = v1;
    } else {
        const float* gp = (const float*)src + gr * 128 + (cb >> 1);
        f32x4 f[4];
#pragma unroll
        for (int j = 0; j < 4; j++) f[j] = *(const f32x4*)(gp + 4 * j);
        *(uint4*)(lp + ((cb + 0) ^ swz)) = packbf8(f[0], f[1]);
        *(uint4*)(lp + ((cb + 16) ^ swz)) = packbf8(f[2], f[3]);
    }
}

// FUSED layer-0: h0 = gelu(mean@Wl0 + x@Wr0 + bl0) + x@Wp + bp; optional fp8 emit (HW cvt).
// Round-12 post-mortem: PIN8 didn't force weight residency (VGPR 84) and dur stayed 47.5us
// with NOTHING saturated (MFMA 7%, VALU 27%, HBM 20%, occ 23% ~= 2 blocks/CU). The kernel
// is a barrier-phased latency chain with too few resident blocks to overlap phases.
// Fix: HALVE the tile to 32 rows -> 2x blocks (3125), LDS 16KB (cap 10 blocks/CU), half
// the acc footprint. More resident blocks => stage/compute/store phases of different
// blocks interleave => latency hidden by TLP (weight L2 traffic doubles but is ~96KB hot).
template <int F32>
__global__ __launch_bounds__(256, 2) void gemmF_kernel(const void* __restrict__ x, const u16* __restrict__ mean,
                                                       const u16* __restrict__ WTl, const u16* __restrict__ WTr,
                                                       const u16* __restrict__ WTp,
                                                       const void* __restrict__ bl, const void* __restrict__ bp,
                                                       const int* __restrict__ mode,
                                                       u16* __restrict__ h0, u8* __restrict__ F8, int emitF8,
                                                       int N) {
    if (mode[1] != F32) return;
    __shared__ u16 lsM[32 * 128];
    __shared__ u16 lsX[32 * 128];
    const int t = threadIdx.x;
    const int lane = t & 63, wave = t >> 6;
    const int m0 = lane & 15, q = lane >> 4;
    const long tb = (long)blockIdx.x * 32;

    // weight fragments for this wave's 2 n-groups (cols 32*wave .. 32*wave+31)
    short8 wl[4][2], wr[4][2], wp[4][2];
#pragma unroll
    for (int ks = 0; ks < 4; ks++)
#pragma unroll
        for (int h = 0; h < 2; h++) {
            const int ro = ((2 * wave + h) * 16 + m0) * 128 + ks * 32 + q * 8;
            wl[ks][h] = *(const short8*)(WTl + ro);
            wr[ks][h] = *(const short8*)(WTr + ro);
            wp[ks][h] = *(const short8*)(WTp + ro);
        }
#pragma unroll
    for (int ks = 0; ks < 4; ks++)
#pragma unroll
        for (int h = 0; h < 2; h++) { PIN8(wl[ks][h]); PIN8(wr[ks][h]); PIN8(wp[ks][h]); }

    stageTile32<0>(mean, lsM, tb, N, t);
    stageTile32<F32>(x, lsX, tb, N, t);
    __syncthreads();

    f32x4 accU[2][2], accR[2][2];
#pragma unroll
    for (int rt = 0; rt < 2; rt++)
#pragma unroll
        for (int h = 0; h < 2; h++) { accU[rt][h] = {0.f, 0.f, 0.f, 0.f}; accR[rt][h] = {0.f, 0.f, 0.f, 0.f}; }

    const int swz = (m0 & 7) << 4;
#pragma unroll
    for (int ks = 0; ks < 4; ks++) {
        short8 aM[2], aX[2];
#pragma unroll
        for (int rt = 0; rt < 2; rt++) {
            const int off = (rt * 16 + m0) * 256 + ((ks * 64 + q * 16) ^ swz);
            aM[rt] = *(const short8*)((const char*)lsM + off);
            aX[rt] = *(const short8*)((const char*)lsX + off);
        }
#pragma unroll
        for (int rt = 0; rt < 2; rt++)
#pragma unroll
            for (int h = 0; h < 2; h++) {
                accU[rt][h] = __builtin_amdgcn_mfma_f32_16x16x32_bf16(wl[ks][h], aM[rt], accU[rt][h], 0, 0, 0);
                accU[rt][h] = __builtin_amdgcn_mfma_f32_16x16x32_bf16(wr[ks][h], aX[rt], accU[rt][h], 0, 0, 0);
                accR[rt][h] = __builtin_amdgcn_mfma_f32_16x16x32_bf16(wp[ks][h], aX[rt], accR[rt][h], 0, 0, 0);
            }
    }

    // epilogue: lane (m0,q) holds rows tb+rt*16+m0, cols (2w+h)*16+q*4+g
    float blv[2][4], bpv[2][4];
#pragma unroll
    for (int h = 0; h < 2; h++)
#pragma unroll
        for (int g = 0; g < 4; g++) {
            const int col = (2 * wave + h) * 16 + q * 4 + g;
            blv[h][g] = ldf(bl, col, F32);
            bpv[h][g] = ldf(bp, col, F32);
        }
#pragma unroll
    for (int rt = 0; rt < 2; rt++) {
        const long row = tb + rt * 16 + m0;
        if (row < N) {
#pragma unroll
            for (int h = 0; h < 2; h++) {
                float v[4];
#pragma unroll
                for (int g = 0; g < 4; g++)
                    v[g] = gelu_f(accU[rt][h][g] + blv[h][g]) + accR[rt][h][g] + bpv[h][g];
                const int col0 = (2 * wave + h) * 16 + q * 4;
                u64 pk = (u64)f2b(v[0]) | ((u64)f2b(v[1]) << 16) | ((u64)f2b(v[2]) << 32) | ((u64)f2b(v[3]) << 48);
                *(u64*)(h0 + (size_t)row * 128 + col0) = pk;
                if (emitF8)
                    *(u32*)(F8 + (size_t)row * 128 + col0) = pk4_fp8(v[0], v[1], v[2], v[3]);
            }
        }
    }
}

// h1 = gelu(mean1@Wl1 + h0@Wr1 + bl1) + h0   (h1 aliases mean: block stages its own 32
// rows into LDS before writing them; blocks touch disjoint rows). Residual from LDS tile.
__global__ __launch_bounds__(256, 2) void gemm1_kernel(const u16* __restrict__ h0, const u16* mean,
                                                       const u16* __restrict__ WTl, const u16* __restrict__ WTr,
                                                       const void* __restrict__ bl, const int* __restrict__ mode,
                                                       u16* h1, int N) {
    __shared__ u16 lsM[32 * 128];
    __shared__ u16 lsH[32 * 128];
    const int t = threadIdx.x;
    const int lane = t & 63, wave = t >> 6;
    const int m0 = lane & 15, q = lane >> 4;
    const int f32 = mode[1];
    const long tb = (long)blockIdx.x * 32;

    short8 wl[4][2], wr[4][2];
#pragma unroll
    for (int ks = 0; ks < 4; ks++)
#pragma unroll
        for (int h = 0; h < 2; h++) {
            const int ro = ((2 * wave + h) * 16 + m0) * 128 + ks * 32 + q * 8;
            wl[ks][h] = *(const short8*)(WTl + ro);
            wr[ks][h] = *(const short8*)(WTr + ro);
        }
#pragma unroll
    for (int ks = 0; ks < 4; ks++)
#pragma unroll
        for (int h = 0; h < 2; h++) { PIN8(wl[ks][h]); PIN8(wr[ks][h]); }

    stageTile32<0>(mean, lsM, tb, N, t);
    stageTile32<0>(h0, lsH, tb, N, t);
    __syncthreads();

    f32x4 acc[2][2];
#pragma unroll
    for (int rt = 0; rt < 2; rt++)
#pragma unroll
        for (int h = 0; h < 2; h++) acc[rt][h] = {0.f, 0.f, 0.f, 0.f};

    const int swz = (m0 & 7) << 4;
#pragma unroll
    for (int ks = 0; ks < 4; ks++) {
        short8 aM[2], aH[2];
#pragma unroll
        for (int rt = 0; rt < 2; rt++) {
            const int off = (rt * 16 + m0) * 256 + ((ks * 64 + q * 16) ^ swz);
            aM[rt] = *(const short8*)((const char*)lsM + off);
            aH[rt] = *(const short8*)((const char*)lsH + off);
        }
#pragma unroll
        for (int rt = 0; rt < 2; rt++)
#pragma unroll
            for (int h = 0; h < 2; h++) {
                acc[rt][h] = __builtin_amdgcn_mfma_f32_16x16x32_bf16(wl[ks][h], aM[rt], acc[rt][h], 0, 0, 0);
                acc[rt][h] = __builtin_amdgcn_mfma_f32_16x16x32_bf16(wr[ks][h], aH[rt], acc[rt][h], 0, 0, 0);
            }
    }

    float blv[2][4];
#pragma unroll
    for (int h = 0; h < 2; h++)
#pragma unroll
        for (int g = 0; g < 4; g++) blv[h][g] = ldf(bl, (2 * wave + h) * 16 + q * 4 + g, f32);

#pragma unroll
    for (int rt = 0; rt < 2; rt++) {
        const long row = tb + rt * 16 + m0;
        if (row < N) {
#pragma unroll
            for (int h = 0; h < 2; h++) {
                const int col0 = (2 * wave + h) * 16 + q * 4;
                // residual: old h0 values from the staged (swizzled) LDS tile
                const int rb = (rt * 16 + m0) * 256 + (((2 * wave + h) * 32 + q * 8) ^ swz);
                const u64 old = *(const u64*)((const char*)lsH + rb);
                float v[4];
#pragma unroll
                for (int g = 0; g < 4; g++)
                    v[g] = gelu_f(acc[rt][h][g] + blv[h][g]) + b2f((u16)(old >> (16 * g)));
                u64 pk = (u64)f2b(v[0]) | ((u64)f2b(v[1]) << 16) | ((u64)f2b(v[2]) << 32) | ((u64)f2b(v[3]) << 48);
                *(u64*)(h1 + (size_t)row * 128 + col0) = pk;
            }
        }
    }
}

// out = alpha*rr + (1-alpha)*(gelu(h1@Ws1+bs1)@Ws2 + bs2)
__global__ __launch_bounds__(256, 4) void score_kernel(const u16* __restrict__ h1, const u16* __restrict__ WTs,
                                                       const void* __restrict__ bs1, const void* __restrict__ w2,
                                                       const void* __restrict__ bs2, const void* __restrict__ rr,
                                                       const void* __restrict__ alpha_p, const int* __restrict__ mode,
                                                       void* __restrict__ out, int N) {
    const int lane = threadIdx.x & 63, wave = threadIdx.x >> 6;
    const int m0 = lane & 15, q = lane >> 4;
    const int f32 = mode[1];
    const long rowBase = (long)blockIdx.x * 128 + wave * 32;
    f32x4 acc[2][4];
#pragma unroll
    for (int r = 0; r < 2; r++)
#pragma unroll
        for (int n = 0; n < 4; n++) acc[r][n] = {0.f, 0.f, 0.f, 0.f};
#pragma unroll
    for (int ks = 0; ks < 4; ++ks) {
        const int k = ks * 32 + q * 8;
        short8 bf[4];
#pragma unroll
        for (int n = 0; n < 4; n++) bf[n] = *(const short8*)(WTs + (n * 16 + m0) * 128 + k);
#pragma unroll
        for (int r = 0; r < 2; r++) {
            long row = rowBase + r * 16 + m0;
            if (row >= N) row = N - 1;
            short8 a = *(const short8*)(h1 + (size_t)row * 128 + k);
#pragma unroll
            for (int n = 0; n < 4; n++)
                acc[r][n] = __builtin_amdgcn_mfma_f32_16x16x32_bf16(a, bf[n], acc[r][n], 0, 0, 0);
        }
    }
    float alpha = 1.f / (1.f + expf(-ldf(alpha_p, 0, f32)));
    float bs2v = ldf(bs2, 0, f32);
    float w2v[4], b1v[4];
#pragma unroll
    for (int n = 0; n < 4; n++) {
        int col = n * 16 + m0;
        w2v[n] = ldf(w2, col, f32);
        b1v[n] = ldf(bs1, col, f32);
    }
#pragma unroll
    for (int r = 0; r < 2; r++) {
        float s[4] = {0.f, 0.f, 0.f, 0.f};
#pragma unroll
        for (int n = 0; n < 4; n++)
#pragma unroll
            for (int g = 0; g < 4; g++) s[g] += gelu_f(acc[r][n][g] + b1v[n]) * w2v[n];
#pragma unroll
        for (int g = 0; g < 4; g++) {
            s[g] += __shfl_xor(s[g], 1, 64);
            s[g] += __shfl_xor(s[g], 2, 64);
            s[g] += __shfl_xor(s[g], 4, 64);
            s[g] += __shfl_xor(s[g], 8, 64);
        }
        if (m0 == 0) {
            long row0 = rowBase + r * 16 + q * 4;
#pragma unroll
            for (int g = 0; g < 4; g++) {
                long row = row0 + g;
                if (row < N) {
                    float sc = s[g] + bs2v;
                    float v = alpha * ldf(rr, (int)row, f32) + (1.f - alpha) * sc;
                    if (f32) ((float*)out)[row] = v; else ((u16*)out)[row] = f2b(v);
                }
            }
        }
    }
}

extern "C" void kernel_launch(void* const* d_in, const int* in_sizes, int n_in,
                              void* d_out, int out_size, void* d_ws, size_t ws_size,
                              hipStream_t stream) {
    const void* x = d_in[0];
    const int* ei = (const int*)d_in[1];
    const void* rr = d_in[2];
    const void* Wp = d_in[3];
    const void* bp = d_in[4];
    const void* Wl0 = d_in[5];
    const void* bl0 = d_in[6];
    const void* Wr0 = d_in[7];
    const void* Wl1 = d_in[8];
    const void* bl1 = d_in[9];
    const void* Wr1 = d_in[10];
    const void* Ws1 = d_in[11];
    const void* bs1 = d_in[12];
    const void* Ws2 = d_in[13];
    const void* bs2 = d_in[14];
    const void* alpha = d_in[15];

    const int N = in_sizes[0] / 128;
    const int E = in_sizes[1] / 2;
    const int NP = ((N + 2047) / 2048) * 2048;
    const int NB = NP / 2048;
    const int chunks = (E + 2047) / 2048;        // CHUNK=2048
    int shift = 0;
    while (((N - 1) >> shift) >= 1024) shift++;   // K=1024 buckets

    char* w = (char*)d_ws;
    size_t used = 0;
    auto alloc = [&](size_t b) { char* p = w + used; used += (b + 255) & ~(size_t)255; return p; };
    int* mode = (int*)alloc(256);
    int* deg = (int*)alloc((size_t)NP * 4);      // legacy path only
    int* bcnt = (int*)alloc(1024 * 4);
    int* boff = (int*)alloc(1025 * 4);
    int* chist = (int*)alloc((size_t)chunks * 1024 * 4);
    int* off = (int*)alloc((size_t)(NP + 64) * 4);
    int* part = (int*)alloc(64 * 4);
    int* sorted = (int*)alloc((size_t)E * 4);
    u16* T = (u16*)alloc(90112 * 2);
    u16* meanb = (u16*)alloc((size_t)NP * 128 * 2);
    u16* h0 = (u16*)alloc((size_t)NP * 128 * 2);
    u16* h1 = meanb;  // alias: gemm1 blocks stage their mean rows before writing them
    size_t usedBase = used;
    size_t fbytes = (size_t)NP * 128;
    if ((size_t)E * 8 > fbytes) fbytes = (size_t)E * 8;
    u8* F = (u8*)alloc(fbytes);      // fp8 gather table; doubles as bucket-sort pairs buffer
    size_t usedFull = used;
    u64* pairs = (u64*)F;

    if (ws_size < 4096) {
        fallback_kernel<<<(N + 255) / 256, 256, 0, stream>>>(rr, alpha, nullptr, d_out, N);
        return;
    }
    probe_kernel<<<1, 64, 0, stream>>>(ei, (const u16*)x, mode);
    if (usedBase > ws_size) {
        fallback_kernel<<<(N + 255) / 256, 256, 0, stream>>>(rr, alpha, mode, d_out, N);
        return;
    }
    const bool fp8Path = (usedFull <= ws_size);
    // chunkScanPre supports chunks <= 64 lanes x 32/lane = 2048
    const bool bucketPath = fp8Path && ((1 << shift) <= 2048) && (chunks <= 2048);

    prep_kernel<<<(90112 + 255) / 256, 256, 0, stream>>>(Wp, Wl0, Wr0, Wl1, Wr1, Ws1, mode, T);

    if (bucketPath) {
        // atomic-free CSR build: LDS histograms + prefix scans; deg/off derived in bucketFill2
        bucketHist2_kernel<<<chunks, 256, 0, stream>>>(ei, E, N, mode, shift, chist, chunks);
        chunkScanPre_kernel<<<256, 256, 0, stream>>>(chist, bcnt, chunks);
        scanK_kernel<<<1, 256, 0, stream>>>(bcnt, boff);
        bucketScatter2_kernel<<<chunks, 256, 0, stream>>>(ei, E, N, mode, shift, chist, boff, pairs, chunks);
        bucketFill2_kernel<<<1024, 256, 0, stream>>>(pairs, boff, off, sorted, shift, E, N);
    } else {
        hipMemsetAsync(deg, 0, (size_t)NP * 4, stream);
        hist_kernel<<<(E + 255) / 256, 256, 0, stream>>>(ei, E, N, mode, deg);
        scanA_kernel<<<NB, 256, 0, stream>>>(deg, part);
        scanB_kernel<<<1, 64, 0, stream>>>(part, NB);
        scanC_kernel<<<NB, 256, 0, stream>>>(deg, part, off);
        fill_kernel<<<(E + 255) / 256, 256, 0, stream>>>(ei, E, N, mode, off, deg, sorted);
    }

    const int gemmGrid32 = (N + 31) / 32;
    const int nodeBlocks = (N + 3) / 4;
    const int NE = N * 64;  // u16-pairs per feature matrix
    const int cvtGrid = (NE + 255) / 256;

    if (fp8Path) {
        // layer 0: x -> fp8 table -> gather -> fused GEMM (emits fp8 h0 table)
        cvt8_kernel<0><<<cvtGrid, 256, 0, stream>>>(x, F, mode, NE, 1);
        cvt8_kernel<1><<<cvtGrid, 256, 0, stream>>>(x, F, mode, NE, 1);
        sagg8_kernel<<<nodeBlocks, 256, 0, stream>>>(F, off, sorted, meanb, N, E);
        gemmF_kernel<0><<<gemmGrid32, 256, 0, stream>>>(x, meanb, T + 16384, T + 32768, T + 0, bl0, bp, mode, h0, F, 1, N);
        gemmF_kernel<1><<<gemmGrid32, 256, 0, stream>>>(x, meanb, T + 16384, T + 32768, T + 0, bl0, bp, mode, h0, F, 1, N);
        // layer 1: gather fp8(h0) -> GEMM (+residual from LDS)
        sagg8_kernel<<<nodeBlocks, 256, 0, stream>>>(F, off, sorted, meanb, N, E);
    } else {
        // bf16 direct-gather fallback (no fp8 table space)
        saggb_kernel<0><<<nodeBlocks, 256, 0, stream>>>(x, off, sorted, meanb, N, E, mode, 1);
        saggb_kernel<1><<<nodeBlocks, 256, 0, stream>>>(x, off, sorted, meanb, N, E, mode, 1);
        gemmF_kernel<0><<<gemmGrid32, 256, 0, stream>>>(x, meanb, T + 16384, T + 32768, T + 0, bl0, bp, mode, h0, nullptr, 0, N);
        gemmF_kernel<1><<<gemmGrid32, 256, 0, stream>>>(x, meanb, T + 16384, T + 32768, T + 0, bl0, bp, mode, h0, nullptr, 0, N);
        saggb_kernel<0><<<nodeBlocks, 256, 0, stream>>>(h0, off, sorted, meanb, N, E, mode, 0);
    }
    gemm1_kernel<<<gemmGrid32, 256, 0, stream>>>(h0, meanb, T + 49152, T + 65536, bl1, mode, h1, N);
    score_kernel<<<(N + 127) / 128, 256, 0, stream>>>(h1, T + 81920, bs1, Ws2, bs2, rr, alpha, mode, d_out, N);
}

// Round 15
// 353.714 us; speedup vs baseline: 1.0623x; 1.0623x over previous
//
#include <hip/hip_runtime.h>

typedef unsigned short u16;
typedef unsigned char  u8;
typedef unsigned int   u32;
typedef unsigned long long u64;
typedef __attribute__((ext_vector_type(8))) short short8;
typedef __attribute__((ext_vector_type(4))) float f32x4;
typedef __attribute__((ext_vector_type(2))) float f32x2;

// keep loaded fragments materialized (asm output can't be rematerialized)
#define PIN8(v) asm volatile("" : "+v"(v))

__device__ __forceinline__ float b2f(u16 u) { return __uint_as_float(((u32)u) << 16); }
__device__ __forceinline__ u16 f2b(float f) {
    u32 i = __float_as_uint(f);
    return (u16)((i + 0x7FFFu + ((i >> 16) & 1u)) >> 16);   // RNE
}
__device__ __forceinline__ float gelu_f(float v) {
    return 0.5f * v * (1.f + erff(v * 0.70710678118654752f));  // exact-erf GELU
}
__device__ __forceinline__ float ldf(const void* p, int i, int f32) {
    return f32 ? ((const float*)p)[i] : b2f(((const u16*)p)[i]);
}

// ---- OCP e4m3fn decode/encode (manual fallback) ----
__device__ __forceinline__ float fp8_dec(u32 v) {  // low 8 bits used
    u32 bits = ((v & 0x80u) << 24) | ((v & 0x7Fu) << 20);
    return __uint_as_float(bits) * 1.3292279957849159e36f;  // *2^120
}
__device__ __forceinline__ u32 fp8_enc(float x) {
    u32 b = __float_as_uint(x);
    u32 s = (b >> 24) & 0x80u;
    float ax = fminf(__uint_as_float(b & 0x7FFFFFFFu), 448.f);
    u32 r;
    if (ax < 0.015625f) {
        r = (u32)(ax * 512.f + 0.5f);
    } else {
        u32 ab = __float_as_uint(ax);
        u32 rb = ab + 0x7FFFFu + ((ab >> 20) & 1u);   // RNE to 3-bit mantissa
        int e8 = (int)(rb >> 23) - 120;
        u32 m = (rb >> 20) & 7u;
        if (e8 > 15) { e8 = 15; m = 6u; }
        r = ((u32)e8 << 3) | m;
    }
    return s | r;
}

// HW fp8 converters (gfx950: OCP e4m3fn) with manual fallback
__device__ __forceinline__ f32x2 dec2_fp8(u32 v) {  // low 16 bits = 2 fp8
#if __has_builtin(__builtin_amdgcn_cvt_pk_f32_fp8)
    return __builtin_amdgcn_cvt_pk_f32_fp8((int)v, false);
#else
    f32x2 r; r[0] = fp8_dec(v); r[1] = fp8_dec(v >> 8); return r;
#endif
}
__device__ __forceinline__ u32 pk4_fp8(float v0, float v1, float v2, float v3) {
#if __has_builtin(__builtin_amdgcn_cvt_pk_fp8_f32)
    int p = __builtin_amdgcn_cvt_pk_fp8_f32(v0, v1, 0, false);
    p = __builtin_amdgcn_cvt_pk_fp8_f32(v2, v3, p, true);
    return (u32)p;
#else
    return fp8_enc(v0) | (fp8_enc(v1) << 8) | (fp8_enc(v2) << 16) | (fp8_enc(v3) << 24);
#endif
}

// ---------------- dtype probe ----------------
__global__ void probe_kernel(const int* __restrict__ ei, const u16* __restrict__ xw,
                             int* __restrict__ mode) {
    int lane = threadIdx.x;  // 64
    int v = (lane < 8) ? ei[2 * lane + 1] : 0;
    unsigned long long nz = __ballot(v != 0);
    u16 h = xw[2 * lane];
    int e = (h >> 7) & 0xFF;
    unsigned long long pl = __ballot(e >= 100 && e <= 140);
    if (lane == 0) {
        mode[0] = (nz == 0ULL) ? 1 : 0;
        mode[1] = (__popcll(pl) >= 48) ? 0 : 1;
    }
}

// ---------------- fallback ----------------
__global__ __launch_bounds__(256) void fallback_kernel(const void* __restrict__ rr,
                                                       const void* __restrict__ al,
                                                       const int* __restrict__ mode,
                                                       void* __restrict__ out, int N) {
    int i = blockIdx.x * 256 + threadIdx.x;
    if (i >= N) return;
    int f32 = mode ? mode[1] : 0;
    float a = 1.f / (1.f + expf(-ldf(al, 0, f32)));
    float v = a * ldf(rr, i, f32);
    if (f32) ((float*)out)[i] = v; else ((u16*)out)[i] = f2b(v);
}

// ---------------- CSR build (legacy global-atomic path, ws fallback) ----------------
__global__ __launch_bounds__(256) void hist_kernel(const int* __restrict__ ei, int E, int N,
                                                   const int* __restrict__ mode,
                                                   int* __restrict__ deg) {
    int i = blockIdx.x * 256 + threadIdx.x;
    if (i >= E) return;
    int m64 = mode[0];
    int d = m64 ? ei[2 * E + 2 * i] : ei[E + i];
    if ((unsigned)d < (unsigned)N) atomicAdd(&deg[d], 1);
}

// per-chunk bucket histogram, CHUNK=2048, 256 threads. NO GLOBAL ATOMICS. chist [bucket][chunk].
__global__ __launch_bounds__(256) void bucketHist2_kernel(const int* __restrict__ ei, int E, int N,
                                                          const int* __restrict__ mode, int shift,
                                                          int* __restrict__ chist, int chunks) {
    __shared__ int h[1024];
    int t = threadIdx.x;
#pragma unroll
    for (int j = 0; j < 4; j++) h[t + j * 256] = 0;
    __syncthreads();
    const int m64 = mode[0];
    const int base = blockIdx.x * 2048;
#pragma unroll
    for (int j = 0; j < 8; j++) {
        int i = base + j * 256 + t;
        if (i < E) {
            int d = m64 ? ei[2 * E + 2 * i] : ei[E + i];
            if ((unsigned)d < (unsigned)N) atomicAdd(&h[d >> shift], 1);
        }
    }
    __syncthreads();
#pragma unroll
    for (int j = 0; j < 4; j++) {
        int b = t + j * 256;
        chist[(size_t)b * chunks + blockIdx.x] = h[b];
    }
}

__global__ __launch_bounds__(256) void scanA_kernel(const int* __restrict__ deg,
                                                    int* __restrict__ part) {
    int t = threadIdx.x, lane = t & 63, wv = t >> 6;
    size_t base = (size_t)blockIdx.x * 2048 + (size_t)t * 8;
    int s = 0;
#pragma unroll
    for (int j = 0; j < 8; j++) s += deg[base + j];
    for (int m = 1; m < 64; m <<= 1) s += __shfl_xor(s, m, 64);
    __shared__ int ws4[4];
    if (lane == 0) ws4[wv] = s;
    __syncthreads();
    if (t == 0) part[blockIdx.x] = ws4[0] + ws4[1] + ws4[2] + ws4[3];
}

__global__ void scanB_kernel(int* __restrict__ part, int nb) {
    int lane = threadIdx.x;
    int v = (lane < nb) ? part[lane] : 0;
    int orig = v;
    for (int d = 1; d < 64; d <<= 1) {
        int o = __shfl_up(v, d, 64);
        if (lane >= d) v += o;
    }
    if (lane < nb) part[lane] = v - orig;  // exclusive
}

__global__ __launch_bounds__(256) void scanC_kernel(const int* __restrict__ deg,
                                                    const int* __restrict__ part,
                                                    int* __restrict__ off) {
    int t = threadIdx.x, lane = t & 63, wv = t >> 6;
    size_t base = (size_t)blockIdx.x * 2048 + (size_t)t * 8;
    int v[8];
    int s = 0;
#pragma unroll
    for (int j = 0; j < 8; j++) { v[j] = deg[base + j]; s += v[j]; }
    int incl = s;
    for (int d = 1; d < 64; d <<= 1) {
        int o = __shfl_up(incl, d, 64);
        if (lane >= d) incl += o;
    }
    __shared__ int wsum[4];
    if (lane == 63) wsum[wv] = incl;
    __syncthreads();
    int pre = part[blockIdx.x] + (incl - s);
    for (int w = 0; w < wv; w++) pre += wsum[w];
#pragma unroll
    for (int j = 0; j < 8; j++) { off[base + j] = pre; pre += v[j]; }
    if (blockIdx.x == gridDim.x - 1 && t == 255) off[base + 8] = pre;  // off[NP]
}

// exclusive scan of 1024 bucket counts (one block)
__global__ __launch_bounds__(256) void scanK_kernel(const int* __restrict__ bcnt,
                                                    int* __restrict__ boff) {
    int t = threadIdx.x, lane = t & 63, wv = t >> 6;
    int v[4];
    int s = 0;
#pragma unroll
    for (int j = 0; j < 4; j++) { v[j] = bcnt[t * 4 + j]; s += v[j]; }
    int incl = s;
    for (int d = 1; d < 64; d <<= 1) {
        int o = __shfl_up(incl, d, 64);
        if (lane >= d) incl += o;
    }
    __shared__ int wsum[4];
    if (lane == 63) wsum[wv] = incl;
    __syncthreads();
    int pre = incl - s;
    for (int w = 0; w < wv; w++) pre += wsum[w];
#pragma unroll
    for (int j = 0; j < 4; j++) { boff[t * 4 + j] = pre; pre += v[j]; }
    if (t == 255) boff[1024] = pre;
}

// one WAVE per bucket: chist[b][c] -> exclusive prefix WITHIN row; writes bcnt[b].
__global__ __launch_bounds__(256) void chunkScanPre_kernel(int* __restrict__ chist,
                                                           int* __restrict__ bcnt, int chunks) {
    const int b = (blockIdx.x * 256 + threadIdx.x) >> 6;
    if (b >= 1024) return;
    const int lane = threadIdx.x & 63;
    const int per = (chunks + 63) >> 6;   // <= 32 (bucketPath gated at chunks<=2048)
    int* row = chist + (size_t)b * chunks;
    int v[32];
    int sum = 0;
#pragma unroll
    for (int j = 0; j < 32; j++) {
        int c = lane * per + j;
        v[j] = (j < per && c < chunks) ? row[c] : 0;
        sum += v[j];
    }
    int pre = sum;
    for (int d = 1; d < 64; d <<= 1) {
        int o = __shfl_up(pre, d, 64);
        if (lane >= d) pre += o;
    }
    if (lane == 63) bcnt[b] = pre;        // row total (inclusive of all lanes)
    pre -= sum;                            // exclusive within row
#pragma unroll
    for (int j = 0; j < 32; j++) {
        int c = lane * per + j;
        if (j < per && c < chunks) { row[c] = pre; pre += v[j]; }
    }
}

// single-pass scatter using per-chunk local bases + boff[b] (no global atomics).
__global__ __launch_bounds__(256) void bucketScatter2_kernel(const int* __restrict__ ei, int E, int N,
                                                             const int* __restrict__ mode, int shift,
                                                             const int* __restrict__ cbase,
                                                             const int* __restrict__ boff,
                                                             u64* __restrict__ pairs, int chunks) {
    __shared__ int cur[1024];
    int t = threadIdx.x;
#pragma unroll
    for (int j = 0; j < 4; j++) {
        int b = t + j * 256;
        cur[b] = cbase[(size_t)b * chunks + blockIdx.x] + boff[b];
    }
    __syncthreads();
    const int m64 = mode[0];
    const int base = blockIdx.x * 2048;
#pragma unroll
    for (int j = 0; j < 8; j++) {
        int i = base + j * 256 + t;
        if (i < E) {
            int d = m64 ? ei[2 * E + 2 * i] : ei[E + i];
            if ((unsigned)d >= (unsigned)N) continue;
            int s = m64 ? ei[2 * i] : ei[i];
            if ((unsigned)s >= (unsigned)N) s = 0;
            int p = atomicAdd(&cur[d >> shift], 1);
            pairs[p] = ((u64)(u32)d << 32) | (u32)s;
        }
    }
}

// final fill, two-pass: derive per-node degrees + CSR off[] locally, then place.
__global__ __launch_bounds__(256) void bucketFill2_kernel(const u64* __restrict__ pairs,
                                                          const int* __restrict__ boff,
                                                          int* __restrict__ off,
                                                          int* __restrict__ sorted,
                                                          int shift, int E, int N) {
    __shared__ int cur[2048];
    __shared__ int wsum[4];
    const int b = blockIdx.x;
    const int t = threadIdx.x;
    const int lane = t & 63, wv = t >> 6;
    const int nodes = 1 << shift;          // <= 2048
    const int nbase = b << shift;
    for (int i = t; i < nodes; i += 256) cur[i] = 0;
    __syncthreads();
    const int s0 = boff[b], s1 = boff[b + 1];
    // pass 1: count degrees
    for (int i = s0 + t; i < s1; i += 256) {
        int li = (int)(pairs[i] >> 32) - nbase;
        if ((unsigned)li < (unsigned)nodes) atomicAdd(&cur[li], 1);
    }
    __syncthreads();
    // exclusive scan of cur[0..nodes) + s0; per = nodes/256 rounded up (1..8)
    const int per = (nodes + 255) >> 8;
    int v[8];
    int sum = 0;
#pragma unroll
    for (int j = 0; j < 8; j++) {
        int idx = t * per + j;
        v[j] = (j < per && idx < nodes) ? cur[idx] : 0;
        sum += v[j];
    }
    int incl = sum;
    for (int d = 1; d < 64; d <<= 1) {
        int o = __shfl_up(incl, d, 64);
        if (lane >= d) incl += o;
    }
    if (lane == 63) wsum[wv] = incl;
    __syncthreads();
    int pre = s0 + (incl - sum);
    for (int w = 0; w < wv; w++) pre += wsum[w];
#pragma unroll
    for (int j = 0; j < 8; j++) {
        int idx = t * per + j;
        if (j < per && idx < nodes) {
            cur[idx] = pre;                              // absolute cursor start
            if (nbase + idx <= N) off[nbase + idx] = pre; // CSR offsets (guarded <= N)
            pre += v[j];
        }
    }
    if (t == 255 && nbase + nodes <= N) off[nbase + nodes] = s1;  // idempotent boundary
    __syncthreads();
    // pass 2: place
    for (int i = s0 + t; i < s1; i += 256) {
        u64 pr = pairs[i];
        int li = (int)(pr >> 32) - nbase;
        if ((unsigned)li >= (unsigned)nodes) continue;
        int p = atomicAdd(&cur[li], 1);
        if ((unsigned)p < (unsigned)E) sorted[p] = (int)(u32)pr;
    }
}

// legacy fill (ws fallback)
__global__ __launch_bounds__(256) void fill_kernel(const int* __restrict__ ei, int E, int N,
                                                   const int* __restrict__ mode,
                                                   const int* __restrict__ off,
                                                   int* __restrict__ deg,
                                                   int* __restrict__ sorted) {
    int i = blockIdx.x * 256 + threadIdx.x;
    if (i >= E) return;
    int m64 = mode[0];
    int s = m64 ? ei[2 * i] : ei[i];
    int d = m64 ? ei[2 * E + 2 * i] : ei[E + i];
    if ((unsigned)d >= (unsigned)N) return;
    if ((unsigned)s >= (unsigned)N) s = 0;
    int p = atomicSub(&deg[d], 1) - 1;
    if (p < 0) return;
    int pos = off[d] + p;
    if ((unsigned)pos < (unsigned)E) sorted[pos] = s;
}

// ---------------- weight transpose into bf16 T ----------------
__global__ __launch_bounds__(256) void prep_kernel(const void* __restrict__ Wp, const void* __restrict__ Wl0,
                                                   const void* __restrict__ Wr0, const void* __restrict__ Wl1,
                                                   const void* __restrict__ Wr1, const void* __restrict__ Ws1,
                                                   const int* __restrict__ mode, u16* __restrict__ T) {
    int idx = blockIdx.x * 256 + threadIdx.x;
    int f32 = mode[1];
    if (idx < 81920) {
        int m = idx >> 14, e = idx & 16383, n = e & 127, k = e >> 7;
        const void* s;
        switch (m) {
            case 0: s = Wp; break;
            case 1: s = Wl0; break;
            case 2: s = Wr0; break;
            case 3: s = Wl1; break;
            default: s = Wr1; break;
        }
        T[m * 16384 + n * 128 + k] = f2b(ldf(s, e, f32));
    } else if (idx < 90112) {
        int e = idx - 81920, k = e >> 6, n = e & 63;
        T[81920 + n * 128 + k] = f2b(ldf(Ws1, e, f32));
    }
}

// ---------------- fp8 conversion: H[N][128] -> F[N][128] e4m3 ----------------
template <int F32>
__global__ __launch_bounds__(256) void cvt8_kernel(const void* __restrict__ H, u8* __restrict__ F,
                                                   const int* __restrict__ mode, int NE, int checkMode) {
    if (checkMode && mode[1] != F32) return;
    int i = blockIdx.x * 256 + threadIdx.x;  // pair index
    if (i >= NE) return;
    float x0, x1;
    if (!F32) {
        u32 v = ((const u32*)H)[i];
        x0 = b2f((u16)v); x1 = b2f((u16)(v >> 16));
    } else {
        x0 = ((const float*)H)[2 * i]; x1 = ((const float*)H)[2 * i + 1];
    }
#if __has_builtin(__builtin_amdgcn_cvt_pk_fp8_f32)
    ((u16*)F)[i] = (u16)__builtin_amdgcn_cvt_pk_fp8_f32(x0, x1, 0, false);
#else
    ((u16*)F)[i] = (u16)(fp8_enc(x0) | (fp8_enc(x1) << 8));
#endif
}

// ---------------- fp8 gather aggregation (HW cvt decode) ----------------
// Wave-wide srcs prefetch: lane l vector-loads srcs[s0+l] (one coalesced 256B load covers
// 64 edges), edge srcs via __shfl, row-gathers issue 8-deep back-to-back.
__global__ __launch_bounds__(256) void sagg8_kernel(const u8* __restrict__ F, const int* __restrict__ off,
                                                    const int* __restrict__ srcs, u16* __restrict__ meanO,
                                                    int N, int E) {
    const int node = __builtin_amdgcn_readfirstlane(blockIdx.x * 4 + (threadIdx.x >> 6));
    if (node >= N) return;
    const int lane = threadIdx.x & 63;
    int s0 = off[node], s1 = off[node + 1];
    if (s0 < 0) s0 = 0;
    if (s1 > E) s1 = E;
    if (s1 < s0) s1 = s0;
    const int dg = s1 - s0;
    const float inv = 1.f / (float)(dg > 1 ? dg : 1);
    const u8* Fp = F + lane * 2;
    float a0 = 0.f, a1 = 0.f;
    for (int base = s0; base < s1; base += 64) {
        const int rem = s1 - base;
        const int cnt = rem < 64 ? rem : 64;
        int msrc = srcs[base + (lane < cnt ? lane : 0)];   // one coalesced load = 64 edges
        if ((unsigned)msrc >= (unsigned)N) msrc = 0;
        int e = 0;
        for (; e + 7 < cnt; e += 8) {
            int i0 = __shfl(msrc, e + 0, 64);
            int i1 = __shfl(msrc, e + 1, 64);
            int i2 = __shfl(msrc, e + 2, 64);
            int i3 = __shfl(msrc, e + 3, 64);
            int i4 = __shfl(msrc, e + 4, 64);
            int i5 = __shfl(msrc, e + 5, 64);
            int i6 = __shfl(msrc, e + 6, 64);
            int i7 = __shfl(msrc, e + 7, 64);
            u32 v0 = *(const u16*)(Fp + (size_t)i0 * 128);
            u32 v1 = *(const u16*)(Fp + (size_t)i1 * 128);
            u32 v2 = *(const u16*)(Fp + (size_t)i2 * 128);
            u32 v3 = *(const u16*)(Fp + (size_t)i3 * 128);
            u32 v4 = *(const u16*)(Fp + (size_t)i4 * 128);
            u32 v5 = *(const u16*)(Fp + (size_t)i5 * 128);
            u32 v6 = *(const u16*)(Fp + (size_t)i6 * 128);
            u32 v7 = *(const u16*)(Fp + (size_t)i7 * 128);
            f32x2 d0 = dec2_fp8(v0), d1 = dec2_fp8(v1), d2 = dec2_fp8(v2), d3 = dec2_fp8(v3);
            f32x2 d4 = dec2_fp8(v4), d5 = dec2_fp8(v5), d6 = dec2_fp8(v6), d7 = dec2_fp8(v7);
            a0 += (d0[0] + d1[0]) + (d2[0] + d3[0]) + (d4[0] + d5[0]) + (d6[0] + d7[0]);
            a1 += (d0[1] + d1[1]) + (d2[1] + d3[1]) + (d4[1] + d5[1]) + (d6[1] + d7[1]);
        }
        for (; e + 3 < cnt; e += 4) {
            int i0 = __shfl(msrc, e + 0, 64);
            int i1 = __shfl(msrc, e + 1, 64);
            int i2 = __shfl(msrc, e + 2, 64);
            int i3 = __shfl(msrc, e + 3, 64);
            u32 v0 = *(const u16*)(Fp + (size_t)i0 * 128);
            u32 v1 = *(const u16*)(Fp + (size_t)i1 * 128);
            u32 v2 = *(const u16*)(Fp + (size_t)i2 * 128);
            u32 v3 = *(const u16*)(Fp + (size_t)i3 * 128);
            f32x2 d0 = dec2_fp8(v0), d1 = dec2_fp8(v1), d2 = dec2_fp8(v2), d3 = dec2_fp8(v3);
            a0 += (d0[0] + d1[0]) + (d2[0] + d3[0]);
            a1 += (d0[1] + d1[1]) + (d2[1] + d3[1]);
        }
        for (; e < cnt; ++e) {
            int i0 = __shfl(msrc, e, 64);
            f32x2 d0 = dec2_fp8(*(const u16*)(Fp + (size_t)i0 * 128));
            a0 += d0[0];
            a1 += d0[1];
        }
    }
    *(u32*)(meanO + (size_t)node * 128 + lane * 2) = (u32)f2b(a0 * inv) | ((u32)f2b(a1 * inv) << 16);
}

// ---------------- bf16/f32 direct-gather aggregation (ws fallback) ----------------
template <int F32>
__global__ __launch_bounds__(256) void saggb_kernel(const void* __restrict__ H, const int* __restrict__ off,
                                                    const int* __restrict__ srcs, u16* __restrict__ meanO,
                                                    int N, int E, const int* __restrict__ mode, int mcheck) {
    if (mcheck && mode[1] != F32) return;
    const int node = __builtin_amdgcn_readfirstlane(blockIdx.x * 4 + (threadIdx.x >> 6));
    if (node >= N) return;
    const int lane = threadIdx.x & 63;
    int s0 = off[node], s1 = off[node + 1];
    if (s0 < 0) s0 = 0;
    if (s1 > E) s1 = E;
    if (s1 < s0) s1 = s0;
    const int dg = s1 - s0;
    const float inv = 1.f / (float)(dg > 1 ? dg : 1);
    float a0 = 0.f, a1 = 0.f;
    if (!F32) {
        const u32* Hp = (const u32*)H + lane;   // row = 64 u32
        for (int e = s0; e < s1; ++e) {
            int i0 = srcs[e];
            if ((unsigned)i0 >= (unsigned)N) i0 = 0;
            u32 v0 = Hp[(size_t)i0 << 6];
            a0 += __uint_as_float(v0 << 16);
            a1 += __uint_as_float(v0 & 0xFFFF0000u);
        }
    } else {
        const float* Hp = (const float*)H + 2 * lane;   // row = 128 f32
        for (int e = s0; e < s1; ++e) {
            int i0 = srcs[e];
            if ((unsigned)i0 >= (unsigned)N) i0 = 0;
            const float2 w0 = *(const float2*)(Hp + ((size_t)i0 << 7));
            a0 += w0.x;
            a1 += w0.y;
        }
    }
    *(u32*)(meanO + (size_t)node * 128 + lane * 2) = (u32)f2b(a0 * inv) | ((u32)f2b(a1 * inv) << 16);
}

// ---------------- MFMA GEMM pieces ----------------
__device__ __forceinline__ uint4 packbf8(f32x4 a, f32x4 b) {
    uint4 o;
    o.x = (u32)f2b(a[0]) | ((u32)f2b(a[1]) << 16);
    o.y = (u32)f2b(a[2]) | ((u32)f2b(a[3]) << 16);
    o.z = (u32)f2b(b[0]) | ((u32)f2b(b[1]) << 16);
    o.w = (u32)f2b(b[2]) | ((u32)f2b(b[3]) << 16);
    return o;
}

// Stage a 64-row x 128-col bf16 tile into LDS with XOR swizzle ^((row&7)<<4) (gemm1).
template <int F32>
__device__ __forceinline__ void stageTile(const void* __restrict__ src, u16* __restrict__ lds,
                                          long tb, int N, int t) {
    const int r = t >> 2;
    long gr = tb + r;
    if (gr >= N) gr = N - 1;
    const int cb = (t & 3) * 64;         // byte offset within 256B bf16 row
    const int swz = (r & 7) << 4;
    char* lp = (char*)lds + r * 256;
    if (!F32) {
        const char* gp = (const char*)src + gr * 256 + cb;
        uint4 v0 = *(const uint4*)(gp + 0);
        uint4 v1 = *(const uint4*)(gp + 16);
        uint4 v2 = *(const uint4*)(gp + 32);
        uint4 v3 = *(const uint4*)(gp + 48);
        *(uint4*)(lp + ((cb + 0) ^ swz)) = v0;
        *(uint4*)(lp + ((cb + 16) ^ swz)) = v1;
        *(uint4*)(lp + ((cb + 32) ^ swz)) = v2;
        *(uint4*)(lp + ((cb + 48) ^ swz)) = v3;
    } else {
        const float* gp = (const float*)src + gr * 128 + (cb >> 1);
        f32x4 f[8];
#pragma unroll
        for (int j = 0; j < 8; j++) f[j] = *(const f32x4*)(gp + 4 * j);
#pragma unroll
        for (int j = 0; j < 4; j++)
            *(uint4*)(lp + ((cb + 16 * j) ^ swz)) = packbf8(f[2 * j], f[2 * j + 1]);
    }
}

// Stage a 64-row x 128-col bf16 tile with FULL swizzle ^((row&15)<<4) (gemmF v2;
// 16-slot XOR kills the 8-slot aliasing that caused r9/r12's 1.2M bank conflicts).
template <int F32>
__device__ __forceinline__ void stageTileA(const void* __restrict__ src, u16* __restrict__ lds,
                                           long tb, int N, int t) {
    const int r = t >> 2;
    long gr = tb + r;
    if (gr >= N) gr = N - 1;
    const int cb = (t & 3) * 64;
    const int swz = (r & 15) << 4;
    char* lp = (char*)lds + r * 256;
    if (!F32) {
        const char* gp = (const char*)src + gr * 256 + cb;
        uint4 v0 = *(const uint4*)(gp + 0);
        uint4 v1 = *(const uint4*)(gp + 16);
        uint4 v2 = *(const uint4*)(gp + 32);
        uint4 v3 = *(const uint4*)(gp + 48);
        *(uint4*)(lp + ((cb + 0) ^ swz)) = v0;
        *(uint4*)(lp + ((cb + 16) ^ swz)) = v1;
        *(uint4*)(lp + ((cb + 32) ^ swz)) = v2;
        *(uint4*)(lp + ((cb + 48) ^ swz)) = v3;
    } else {
        const float* gp = (const float*)src + gr * 128 + (cb >> 1);
        f32x4 f[8];
#pragma unroll
        for (int j = 0; j < 8; j++) f[j] = *(const f32x4*)(gp + 4 * j);
#pragma unroll
        for (int j = 0; j < 4; j++)
            *(uint4*)(lp + ((cb + 16 * j) ^ swz)) = packbf8(f[2 * j], f[2 * j + 1]);
    }
}

// FUSED layer-0 v2: h0 = gelu(mean@Wl0 + x@Wr0 + bl0) + x@Wp + bp; optional fp8 emit.
// Round-14 BUG FIX: the X A-slab lives at byte offset 16384 (64*128 u16), but the compute
// read it at byte 32768 (two slabs) — reading past lsA into adjacent LDS. One-line fix.
// Structure (r13 theory): block stages its COLUMN-HALF of all 3 weight matrices into LDS
// ONCE (48KB, ^((row&15)<<4) swizzle), then loops row-tiles grid-stride (~6/block),
// staging only the 32KB A-tile per iteration. Weight reads hit LDS (~20cy) not L2.
template <int F32>
__global__ __launch_bounds__(256, 2) void gemmF_kernel(const void* __restrict__ x, const u16* __restrict__ mean,
                                                       const u16* __restrict__ WTl, const u16* __restrict__ WTr,
                                                       const u16* __restrict__ WTp,
                                                       const void* __restrict__ bl, const void* __restrict__ bp,
                                                       const int* __restrict__ mode,
                                                       u16* __restrict__ h0, u8* __restrict__ F8, int emitF8,
                                                       int N) {
    if (mode[1] != F32) return;
    __shared__ u16 lsW[3 * 64 * 128];   // 48KB: [mat][n-row 64][k 128], swizzled
    __shared__ u16 lsA[2 * 64 * 128];   // 32KB: [mat M,X][row 64][k 128], swizzled
    const int t = threadIdx.x;
    const int lane = t & 63, wave = t >> 6;
    const int m0 = lane & 15, q = lane >> 4;
    const int nh = blockIdx.x & 1;       // column half
    const int rg = blockIdx.x >> 1;      // row group (0..255)

    // ---- stage this half's weights once: 3 x 64 n-rows x 256B ----
#pragma unroll
    for (int m = 0; m < 3; m++) {
        const u16* Wm = (m == 0) ? WTl : (m == 1) ? WTr : WTp;
#pragma unroll
        for (int j = 0; j < 4; j++) {
            int c = t + j * 256;                  // 0..1023 chunks of 16B
            int nrow = c >> 4, cb = (c & 15) * 16;
            short8 v = *(const short8*)(Wm + (size_t)(nh * 64 + nrow) * 128 + (cb >> 1));
            *(short8*)((char*)lsW + m * 16384 + nrow * 256 + (cb ^ ((nrow & 15) << 4))) = v;
        }
    }

    // per-lane invariants
    const int colg = nh * 4 + wave;              // global n-group 0..7
    const int wrow = wave * 16 + m0;             // local n-row in half
    const int wswz = m0 << 4;
    float blv[4], bpv[4];
#pragma unroll
    for (int g = 0; g < 4; g++) {
        const int col = colg * 16 + q * 4 + g;
        blv[g] = ldf(bl, col, F32);
        bpv[g] = ldf(bp, col, F32);
    }

    const long tiles = ((long)N + 63) >> 6;
    for (long tile = rg; tile < tiles; tile += 256) {
        const long tb = tile * 64;
        stageTileA<0>(mean, lsA, tb, N, t);
        stageTileA<F32>(x, lsA + 64 * 128, tb, N, t);
        __syncthreads();

        f32x4 accU[4], accR[4];
#pragma unroll
        for (int rt = 0; rt < 4; rt++) { accU[rt] = {0.f, 0.f, 0.f, 0.f}; accR[rt] = {0.f, 0.f, 0.f, 0.f}; }

#pragma unroll
        for (int ks = 0; ks < 4; ks++) {
            const int kb = ks * 64 + q * 16;     // byte k-offset of this lane's slice
            short8 wlF = *(const short8*)((char*)lsW + 0 * 16384 + wrow * 256 + (kb ^ wswz));
            short8 wrF = *(const short8*)((char*)lsW + 1 * 16384 + wrow * 256 + (kb ^ wswz));
            short8 wpF = *(const short8*)((char*)lsW + 2 * 16384 + wrow * 256 + (kb ^ wswz));
#pragma unroll
            for (int rt = 0; rt < 4; rt++) {
                const int ab = (rt * 16 + m0) * 256 + (kb ^ (m0 << 4));
                short8 aM = *(const short8*)((char*)lsA + ab);
                short8 aX = *(const short8*)((char*)lsA + 16384 + ab);   // FIX: X slab at byte 16384
                accU[rt] = __builtin_amdgcn_mfma_f32_16x16x32_bf16(wlF, aM, accU[rt], 0, 0, 0);
                accU[rt] = __builtin_amdgcn_mfma_f32_16x16x32_bf16(wrF, aX, accU[rt], 0, 0, 0);
                accR[rt] = __builtin_amdgcn_mfma_f32_16x16x32_bf16(wpF, aX, accR[rt], 0, 0, 0);
            }
        }

        // epilogue: lane (m0,q) holds rows tb+rt*16+m0, cols colg*16+q*4+g
#pragma unroll
        for (int rt = 0; rt < 4; rt++) {
            const long row = tb + rt * 16 + m0;
            if (row < N) {
                float v[4];
#pragma unroll
                for (int g = 0; g < 4; g++)
                    v[g] = gelu_f(accU[rt][g] + blv[g]) + accR[rt][g] + bpv[g];
                const int col0 = colg * 16 + q * 4;
                u64 pk = (u64)f2b(v[0]) | ((u64)f2b(v[1]) << 16) | ((u64)f2b(v[2]) << 32) | ((u64)f2b(v[3]) << 48);
                *(u64*)(h0 + (size_t)row * 128 + col0) = pk;
                if (emitF8)
                    *(u32*)(F8 + (size_t)row * 128 + col0) = pk4_fp8(v[0], v[1], v[2], v[3]);
            }
        }
        __syncthreads();   // protect lsA before next stage
    }
}

// h1 = gelu(mean1@Wl1 + h0@Wr1 + bl1) + h0   (h1 aliases mean: block stages its rows
// into LDS before writing them; blocks touch disjoint rows). Residual h0 from LDS tile.
// Unchanged r12 structure (weight frags PIN8'd).
__global__ __launch_bounds__(256, 2) void gemm1_kernel(const u16* __restrict__ h0, const u16* mean,
                                                       const u16* __restrict__ WTl, const u16* __restrict__ WTr,
                                                       const void* __restrict__ bl, const int* __restrict__ mode,
                                                       u16* h1, int N) {
    __shared__ u16 lsM[64 * 128];
    __shared__ u16 lsH[64 * 128];
    const int t = threadIdx.x;
    const int lane = t & 63, wave = t >> 6;
    const int m0 = lane & 15, q = lane >> 4;
    const int f32 = mode[1];
    const long tb = (long)blockIdx.x * 64;

    short8 wl[4][2], wr[4][2];
#pragma unroll
    for (int ks = 0; ks < 4; ks++)
#pragma unroll
        for (int h = 0; h < 2; h++) {
            const int ro = ((2 * wave + h) * 16 + m0) * 128 + ks * 32 + q * 8;
            wl[ks][h] = *(const short8*)(WTl + ro);
            wr[ks][h] = *(const short8*)(WTr + ro);
        }
#pragma unroll
    for (int ks = 0; ks < 4; ks++)
#pragma unroll
        for (int h = 0; h < 2; h++) { PIN8(wl[ks][h]); PIN8(wr[ks][h]); }

    stageTile<0>(mean, lsM, tb, N, t);
    stageTile<0>(h0, lsH, tb, N, t);
    __syncthreads();

    f32x4 acc[4][2];
#pragma unroll
    for (int rt = 0; rt < 4; rt++)
#pragma unroll
        for (int h = 0; h < 2; h++) acc[rt][h] = {0.f, 0.f, 0.f, 0.f};

    const int swz = (m0 & 7) << 4;
#pragma unroll
    for (int ks = 0; ks < 4; ks++) {
        short8 aM[4], aH[4];
#pragma unroll
        for (int rt = 0; rt < 4; rt++) {
            const int off = (rt * 16 + m0) * 256 + ((ks * 64 + q * 16) ^ swz);
            aM[rt] = *(const short8*)((const char*)lsM + off);
            aH[rt] = *(const short8*)((const char*)lsH + off);
        }
#pragma unroll
        for (int rt = 0; rt < 4; rt++)
#pragma unroll
            for (int h = 0; h < 2; h++) {
                acc[rt][h] = __builtin_amdgcn_mfma_f32_16x16x32_bf16(wl[ks][h], aM[rt], acc[rt][h], 0, 0, 0);
                acc[rt][h] = __builtin_amdgcn_mfma_f32_16x16x32_bf16(wr[ks][h], aH[rt], acc[rt][h], 0, 0, 0);
            }
    }

    float blv[2][4];
#pragma unroll
    for (int h = 0; h < 2; h++)
#pragma unroll
        for (int g = 0; g < 4; g++) blv[h][g] = ldf(bl, (2 * wave + h) * 16 + q * 4 + g, f32);

#pragma unroll
    for (int rt = 0; rt < 4; rt++) {
        const long row = tb + rt * 16 + m0;
        if (row < N) {
#pragma unroll
            for (int h = 0; h < 2; h++) {
                const int col0 = (2 * wave + h) * 16 + q * 4;
                // residual: old h0 values from the staged (swizzled) LDS tile
                const int rb = (rt * 16 + m0) * 256 + (((2 * wave + h) * 32 + q * 8) ^ swz);
                const u64 old = *(const u64*)((const char*)lsH + rb);
                float v[4];
#pragma unroll
                for (int g = 0; g < 4; g++)
                    v[g] = gelu_f(acc[rt][h][g] + blv[h][g]) + b2f((u16)(old >> (16 * g)));
                u64 pk = (u64)f2b(v[0]) | ((u64)f2b(v[1]) << 16) | ((u64)f2b(v[2]) << 32) | ((u64)f2b(v[3]) << 48);
                *(u64*)(h1 + (size_t)row * 128 + col0) = pk;
            }
        }
    }
}

// out = alpha*rr + (1-alpha)*(gelu(h1@Ws1+bs1)@Ws2 + bs2)
__global__ __launch_bounds__(256, 4) void score_kernel(const u16* __restrict__ h1, const u16* __restrict__ WTs,
                                                       const void* __restrict__ bs1, const void* __restrict__ w2,
                                                       const void* __restrict__ bs2, const void* __restrict__ rr,
                                                       const void* __restrict__ alpha_p, const int* __restrict__ mode,
                                                       void* __restrict__ out, int N) {
    const int lane = threadIdx.x & 63, wave = threadIdx.x >> 6;
    const int m0 = lane & 15, q = lane >> 4;
    const int f32 = mode[1];
    const long rowBase = (long)blockIdx.x * 128 + wave * 32;
    f32x4 acc[2][4];
#pragma unroll
    for (int r = 0; r < 2; r++)
#pragma unroll
        for (int n = 0; n < 4; n++) acc[r][n] = {0.f, 0.f, 0.f, 0.f};
#pragma unroll
    for (int ks = 0; ks < 4; ++ks) {
        const int k = ks * 32 + q * 8;
        short8 bf[4];
#pragma unroll
        for (int n = 0; n < 4; n++) bf[n] = *(const short8*)(WTs + (n * 16 + m0) * 128 + k);
#pragma unroll
        for (int r = 0; r < 2; r++) {
            long row = rowBase + r * 16 + m0;
            if (row >= N) row = N - 1;
            short8 a = *(const short8*)(h1 + (size_t)row * 128 + k);
#pragma unroll
            for (int n = 0; n < 4; n++)
                acc[r][n] = __builtin_amdgcn_mfma_f32_16x16x32_bf16(a, bf[n], acc[r][n], 0, 0, 0);
        }
    }
    float alpha = 1.f / (1.f + expf(-ldf(alpha_p, 0, f32)));
    float bs2v = ldf(bs2, 0, f32);
    float w2v[4], b1v[4];
#pragma unroll
    for (int n = 0; n < 4; n++) {
        int col = n * 16 + m0;
        w2v[n] = ldf(w2, col, f32);
        b1v[n] = ldf(bs1, col, f32);
    }
#pragma unroll
    for (int r = 0; r < 2; r++) {
        float s[4] = {0.f, 0.f, 0.f, 0.f};
#pragma unroll
        for (int n = 0; n < 4; n++)
#pragma unroll
            for (int g = 0; g < 4; g++) s[g] += gelu_f(acc[r][n][g] + b1v[n]) * w2v[n];
#pragma unroll
        for (int g = 0; g < 4; g++) {
            s[g] += __shfl_xor(s[g], 1, 64);
            s[g] += __shfl_xor(s[g], 2, 64);
            s[g] += __shfl_xor(s[g], 4, 64);
            s[g] += __shfl_xor(s[g], 8, 64);
        }
        if (m0 == 0) {
            long row0 = rowBase + r * 16 + q * 4;
#pragma unroll
            for (int g = 0; g < 4; g++) {
                long row = row0 + g;
                if (row < N) {
                    float sc = s[g] + bs2v;
                    float v = alpha * ldf(rr, (int)row, f32) + (1.f - alpha) * sc;
                    if (f32) ((float*)out)[row] = v; else ((u16*)out)[row] = f2b(v);
                }
            }
        }
    }
}

extern "C" void kernel_launch(void* const* d_in, const int* in_sizes, int n_in,
                              void* d_out, int out_size, void* d_ws, size_t ws_size,
                              hipStream_t stream) {
    const void* x = d_in[0];
    const int* ei = (const int*)d_in[1];
    const void* rr = d_in[2];
    const void* Wp = d_in[3];
    const void* bp = d_in[4];
    const void* Wl0 = d_in[5];
    const void* bl0 = d_in[6];
    const void* Wr0 = d_in[7];
    const void* Wl1 = d_in[8];
    const void* bl1 = d_in[9];
    const void* Wr1 = d_in[10];
    const void* Ws1 = d_in[11];
    const void* bs1 = d_in[12];
    const void* Ws2 = d_in[13];
    const void* bs2 = d_in[14];
    const void* alpha = d_in[15];

    const int N = in_sizes[0] / 128;
    const int E = in_sizes[1] / 2;
    const int NP = ((N + 2047) / 2048) * 2048;
    const int NB = NP / 2048;
    const int chunks = (E + 2047) / 2048;        // CHUNK=2048
    int shift = 0;
    while (((N - 1) >> shift) >= 1024) shift++;   // K=1024 buckets

    char* w = (char*)d_ws;
    size_t used = 0;
    auto alloc = [&](size_t b) { char* p = w + used; used += (b + 255) & ~(size_t)255; return p; };
    int* mode = (int*)alloc(256);
    int* deg = (int*)alloc((size_t)NP * 4);      // legacy path only
    int* bcnt = (int*)alloc(1024 * 4);
    int* boff = (int*)alloc(1025 * 4);
    int* chist = (int*)alloc((size_t)chunks * 1024 * 4);
    int* off = (int*)alloc((size_t)(NP + 64) * 4);
    int* part = (int*)alloc(64 * 4);
    int* sorted = (int*)alloc((size_t)E * 4);
    u16* T = (u16*)alloc(90112 * 2);
    u16* meanb = (u16*)alloc((size_t)NP * 128 * 2);
    u16* h0 = (u16*)alloc((size_t)NP * 128 * 2);
    u16* h1 = meanb;  // alias: gemm1 blocks stage their mean rows before writing them
    size_t usedBase = used;
    size_t fbytes = (size_t)NP * 128;
    if ((size_t)E * 8 > fbytes) fbytes = (size_t)E * 8;
    u8* F = (u8*)alloc(fbytes);      // fp8 gather table; doubles as bucket-sort pairs buffer
    size_t usedFull = used;
    u64* pairs = (u64*)F;

    if (ws_size < 4096) {
        fallback_kernel<<<(N + 255) / 256, 256, 0, stream>>>(rr, alpha, nullptr, d_out, N);
        return;
    }
    probe_kernel<<<1, 64, 0, stream>>>(ei, (const u16*)x, mode);
    if (usedBase > ws_size) {
        fallback_kernel<<<(N + 255) / 256, 256, 0, stream>>>(rr, alpha, mode, d_out, N);
        return;
    }
    const bool fp8Path = (usedFull <= ws_size);
    // chunkScanPre supports chunks <= 64 lanes x 32/lane = 2048
    const bool bucketPath = fp8Path && ((1 << shift) <= 2048) && (chunks <= 2048);

    prep_kernel<<<(90112 + 255) / 256, 256, 0, stream>>>(Wp, Wl0, Wr0, Wl1, Wr1, Ws1, mode, T);

    if (bucketPath) {
        // atomic-free CSR build: LDS histograms + prefix scans; deg/off derived in bucketFill2
        bucketHist2_kernel<<<chunks, 256, 0, stream>>>(ei, E, N, mode, shift, chist, chunks);
        chunkScanPre_kernel<<<256, 256, 0, stream>>>(chist, bcnt, chunks);
        scanK_kernel<<<1, 256, 0, stream>>>(bcnt, boff);
        bucketScatter2_kernel<<<chunks, 256, 0, stream>>>(ei, E, N, mode, shift, chist, boff, pairs, chunks);
        bucketFill2_kernel<<<1024, 256, 0, stream>>>(pairs, boff, off, sorted, shift, E, N);
    } else {
        hipMemsetAsync(deg, 0, (size_t)NP * 4, stream);
        hist_kernel<<<(E + 255) / 256, 256, 0, stream>>>(ei, E, N, mode, deg);
        scanA_kernel<<<NB, 256, 0, stream>>>(deg, part);
        scanB_kernel<<<1, 64, 0, stream>>>(part, NB);
        scanC_kernel<<<NB, 256, 0, stream>>>(deg, part, off);
        fill_kernel<<<(E + 255) / 256, 256, 0, stream>>>(ei, E, N, mode, off, deg, sorted);
    }

    const int gemmGrid16 = (N + 63) / 64;
    const int nodeBlocks = (N + 3) / 4;
    const int NE = N * 64;  // u16-pairs per feature matrix
    const int cvtGrid = (NE + 255) / 256;

    if (fp8Path) {
        // layer 0: x -> fp8 table -> gather -> fused GEMM (emits fp8 h0 table)
        cvt8_kernel<0><<<cvtGrid, 256, 0, stream>>>(x, F, mode, NE, 1);
        cvt8_kernel<1><<<cvtGrid, 256, 0, stream>>>(x, F, mode, NE, 1);
        sagg8_kernel<<<nodeBlocks, 256, 0, stream>>>(F, off, sorted, meanb, N, E);
        gemmF_kernel<0><<<512, 256, 0, stream>>>(x, meanb, T + 16384, T + 32768, T + 0, bl0, bp, mode, h0, F, 1, N);
        gemmF_kernel<1><<<512, 256, 0, stream>>>(x, meanb, T + 16384, T + 32768, T + 0, bl0, bp, mode, h0, F, 1, N);
        // layer 1: gather fp8(h0) -> GEMM (+residual from LDS)
        sagg8_kernel<<<nodeBlocks, 256, 0, stream>>>(F, off, sorted, meanb, N, E);
    } else {
        // bf16 direct-gather fallback (no fp8 table space)
        saggb_kernel<0><<<nodeBlocks, 256, 0, stream>>>(x, off, sorted, meanb, N, E, mode, 1);
        saggb_kernel<1><<<nodeBlocks, 256, 0, stream>>>(x, off, sorted, meanb, N, E, mode, 1);
        gemmF_kernel<0><<<512, 256, 0, stream>>>(x, meanb, T + 16384, T + 32768, T + 0, bl0, bp, mode, h0, nullptr, 0, N);
        gemmF_kernel<1><<<512, 256, 0, stream>>>(x, meanb, T + 16384, T + 32768, T + 0, bl0, bp, mode, h0, nullptr, 0, N);
        saggb_kernel<0><<<nodeBlocks, 256, 0, stream>>>(h0, off, sorted, meanb, N, E, mode, 0);
    }
    gemm1_kernel<<<gemmGrid16, 256, 0, stream>>>(h0, meanb, T + 49152, T + 65536, bl1, mode, h1, N);
    score_kernel<<<(N + 127) / 128, 256, 0, stream>>>(h1, T + 81920, bs1, Ws2, bs2, rr, alpha, mode, d_out, N);
}